// Round 7
// baseline (1246.901 us; speedup 1.0000x reference)
//
#include <hip/hip_runtime.h>
#include <hip/hip_bf16.h>
#include <stdint.h>

// ---- types -----------------------------------------------------------------
typedef __bf16 bf16_t;
typedef __bf16 bf16x8 __attribute__((ext_vector_type(8)));
typedef __bf16 bf16x4 __attribute__((ext_vector_type(4)));
typedef float  f32x4  __attribute__((ext_vector_type(4)));

#define MFMA16(a, b, c) __builtin_amdgcn_mfma_f32_16x16x32_bf16((a), (b), (c), 0, 0, 0)

__device__ __forceinline__ void gload_lds16(const void* g, void* l) {
  __builtin_amdgcn_global_load_lds((const __attribute__((address_space(1))) void*)g,
                                   (__attribute__((address_space(3))) void*)l, 16, 0, 0);
}

// ---- problem constants -----------------------------------------------------
// B=2, N=4096, NY=4096, ENC=768, DEC=512, H=8, D=64, SCALE=0.125
// Wq pre-scaled by SCALE*log2(e): scores live in exp2 domain.
#define QSCALE 0.18033688011112042f
#define NE_X   4194304UL
#define NE_Y   6291456UL
#define NE_WQ  262144UL
#define NE_WKV 786432UL
#define NE_WP  262144UL
#define NE_BP  512UL

// ---- detect dtype + decode mask to multiplicative bf16 (1=keep, 0=masked) --
__global__ void detect_and_mask(const uint16_t* __restrict__ xu,
                                const uint8_t* __restrict__ mk,
                                int* __restrict__ flags, bf16_t* __restrict__ mmul) {
  __shared__ int cbf, c3f1, c3f3, cnz;
  const int t = threadIdx.x;
  if (t == 0) { cbf = 0; c3f1 = 0; c3f3 = 0; cnz = 0; }
  __syncthreads();
  if (blockIdx.x == 0) {
    int local = 0;
    for (int i = t; i < 2048; i += 256) {
      uint16_t u = xu[2 * i];
      int e = (u >> 7) & 0xFF;
      if (u == 0 || (e >= 0x66 && e <= 0x88)) local++;
    }
    atomicAdd(&cbf, local);
  }
  int l1 = 0, l3 = 0, lnz = 0;
  for (int i = t; i < 4096; i += 256) {
    uint8_t b = mk[i];
    int p = i & 3;
    if (p == 1 && b == 0x3F) l1++;
    if (p == 3 && b == 0x3F) l3++;
    if (p != 0 && b != 0) lnz++;
  }
  atomicAdd(&c3f1, l1);
  atomicAdd(&c3f3, l3);
  atomicAdd(&cnz, lnz);
  __syncthreads();
  if (blockIdx.x == 0 && t == 0) flags[0] = (cbf > 1536) ? 1 : 0;
  const int fmt = (c3f1 > 0) ? 2 : (c3f3 > 0) ? 3 : (cnz > 0) ? 0 : 1;  // 0=bool8 1=i32 2=bf16 3=f32
  const int i = blockIdx.x * 256 + t;  // 32 blocks x 256 = 8192
  bool on;
  if (fmt == 0)      on = mk[i] != 0;
  else if (fmt == 1) on = ((const int*)mk)[i] != 0;
  else if (fmt == 2) on = (((const uint16_t*)mk)[i] & 0x7FFF) != 0;
  else               on = ((const float*)mk)[i] != 0.0f;
  mmul[i] = on ? (bf16_t)0.0f : (bf16_t)1.0f;  // mask=true means EXCLUDE
}

// ---- convert all float inputs to packed bf16 workspace (Wq pre-scaled) -----
__global__ void convert_all(const void* __restrict__ x, const void* __restrict__ y,
                            const void* __restrict__ wq, const void* __restrict__ wkv,
                            const void* __restrict__ wp, const void* __restrict__ bp,
                            uint16_t* __restrict__ dst, const int* __restrict__ flags) {
  const size_t E0 = NE_X, E1 = E0 + NE_Y, E2 = E1 + NE_WQ, E3 = E2 + NE_WKV,
               E4 = E3 + NE_WP, E5 = E4 + NE_BP;
  size_t i8 = ((size_t)blockIdx.x * 256 + threadIdx.x) * 8;
  if (i8 >= E5) return;
  const void* src; size_t off;
  if      (i8 < E0) { src = x;   off = i8; }
  else if (i8 < E1) { src = y;   off = i8 - E0; }
  else if (i8 < E2) { src = wq;  off = i8 - E1; }
  else if (i8 < E3) { src = wkv; off = i8 - E2; }
  else if (i8 < E4) { src = wp;  off = i8 - E3; }
  else              { src = bp;  off = i8 - E4; }
  const bool isWq = (i8 >= E1 && i8 < E2);
  if (flags[0] && !isWq) {
    *(uint4*)(dst + i8) = *(const uint4*)((const uint16_t*)src + off);
    return;
  }
  float v[8];
  if (flags[0]) {  // bf16 source (Wq path): unpack
    const uint16_t* u = (const uint16_t*)src + off;
    for (int j = 0; j < 8; ++j) {
      union { uint32_t q; float f; } c; c.q = ((uint32_t)u[j]) << 16; v[j] = c.f;
    }
  } else {
    const float* f = (const float*)src + off;
    float4 a = *(const float4*)f;
    float4 b2 = *(const float4*)(f + 4);
    v[0] = a.x; v[1] = a.y; v[2] = a.z; v[3] = a.w;
    v[4] = b2.x; v[5] = b2.y; v[6] = b2.z; v[7] = b2.w;
  }
  const float sc = isWq ? QSCALE : 1.0f;
  union { bf16_t h[8]; uint4 u; } pk;
  for (int j = 0; j < 8; ++j) pk.h[j] = (bf16_t)(v[j] * sc);
  *(uint4*)(dst + i8) = pk.u;
}

// ---- GEMM body: C[M x Nc] = A[M x K] @ W[Nc x K]^T, 128xBN tile, BK=32 -----
// MODE 0: C = bf16 [M x Ncols].
// MODE 1 (BN=128): cols<512 -> K in MFMA A-frag order:
//           Kf byte = (((b*8+h)*64+kt)*8 + mt*2 + kc)*1024 + lane*16 + j*2
//           with lane=quad*16+l16: key=kt*64+mt*16+l16, d=kc*32+quad*8+j.
//         cols>=512 -> V in MFMA B-frag order, mask-zeroed:
//           Vf byte = (((b*8+h)*64+kt)*8 + dt*2+kc)*1024 + lane*16 + j*2
//           with lane=jq*16+l15: d=dt*16+l15, key=kt*64+kc*32+jq*8+j.
//         `bias` carries mmul (bf16 0/1 per [b*4096+ny]).
// MODE 2: C = output, + bias, fp32 or bf16 per flags[0].
template <int K, int MODE, int BN>
__device__ __forceinline__ void gemm_body(char* lds,
    const bf16_t* __restrict__ A, const bf16_t* __restrict__ W,
    const bf16_t* __restrict__ bias, void* __restrict__ C,
    bf16_t* __restrict__ Kf, bf16_t* __restrict__ Vf,
    const int* __restrict__ flags, int Ncols, int bx, int by) {
  constexpr int MT = (BN == 128) ? 4 : 2;      // m-tiles per wave
  char* ldsA = lds;
  char* ldsW = lds + 8192;
  const int t = threadIdx.x;
  const int w = t >> 6, lane = t & 63, quad = lane >> 4, l16 = lane & 15;
  const int wr = (BN == 128) ? (w >> 1) : w;
  const int wc = (BN == 128) ? (w & 1) : 0;
  const int m0 = by * 128, n0 = bx * BN;

  f32x4 acc[MT][4] = {};
  const int rowS = t >> 2, uS = t & 3;

  for (int k0 = 0; k0 < K; k0 += 32) {
    __syncthreads();
    for (int i = 0; i < 2; ++i) {
      int row = i * 64 + rowS;
      int c = uS ^ ((row >> 1) & 3);
      gload_lds16(A + (size_t)(m0 + row) * K + k0 + c * 8, ldsA + i * 4096 + w * 1024);
    }
    for (int i = 0; i < BN / 64; ++i) {
      int row = i * 64 + rowS;
      int c = uS ^ ((row >> 1) & 3);
      gload_lds16(W + (size_t)(n0 + row) * K + k0 + c * 8, ldsW + i * 4096 + w * 1024);
    }
    __syncthreads();
    bf16x8 af[MT], bfr[4];
    for (int mt = 0; mt < MT; ++mt) {
      int row = wr * (MT * 16) + mt * 16 + l16;
      int us = quad ^ ((row >> 1) & 3);
      af[mt] = *(const bf16x8*)(ldsA + row * 64 + us * 16);
    }
    for (int nt = 0; nt < 4; ++nt) {
      int row = wc * 64 + nt * 16 + l16;
      int us = quad ^ ((row >> 1) & 3);
      bfr[nt] = *(const bf16x8*)(ldsW + row * 64 + us * 16);
    }
    for (int mt = 0; mt < MT; ++mt)
      for (int nt = 0; nt < 4; ++nt)
        acc[mt][nt] = MFMA16(af[mt], bfr[nt], acc[mt][nt]);
  }

  const int mbase = m0 + wr * (MT * 16);
  for (int nt = 0; nt < 4; ++nt) {
    const int col = n0 + wc * 64 + nt * 16 + l16;
    if (MODE == 1 && col >= 512) {
      const int hd = col - 512;                  // h*64 + d
      const int hh = hd >> 6, d = hd & 63;
      const int dt = d >> 4, l15 = d & 15;
      for (int mt = 0; mt < MT; ++mt) {
        int m = mbase + mt * 16 + quad * 4;      // +r over r
        int bb = m >> 12, keyg = m & 4095;
        int kt = keyg >> 6, keyin = keyg & 63;
        int kc = (keyin >> 5) & 1, jq = (keyin >> 3) & 3, j0 = keyin & 7;  // j0 in {0,4}
        const bf16_t* mmp = bias + bb * 4096 + keyg;
        union { bf16_t h4[4]; uint2 u; } pk;
        for (int r = 0; r < 4; ++r) pk.h4[r] = (bf16_t)(acc[mt][nt][r] * (float)mmp[r]);
        size_t base = (((size_t)(bb * 8 + hh) * 64 + kt) * 8 + dt * 2 + kc) * 1024
                      + (jq * 16 + l15) * 16 + j0 * 2;
        *(uint2*)((char*)Vf + base) = pk.u;
      }
    } else if (MODE == 1) {
      // K half -> A-fragment-order scatter (4 x 2B stores per (mt,nt))
      const int hh = col >> 6, d = col & 63;
      const int kc = d >> 5, qd = (d >> 3) & 3, j = d & 7;
      for (int mt = 0; mt < MT; ++mt) {
        int m = mbase + mt * 16 + quad * 4;
        int bb = m >> 12, keyg = m & 4095;
        int kt = keyg >> 6, mtk = (keyg >> 4) & 3, l16k = keyg & 15;  // l16k = quad*4
        char* base = (char*)Kf + (((size_t)(bb * 8 + hh) * 64 + kt) * 8 + mtk * 2 + kc) * 1024
                     + (qd * 16 + l16k) * 16 + j * 2;
        for (int r = 0; r < 4; ++r)
          *(bf16_t*)(base + r * 16) = (bf16_t)acc[mt][nt][r];
      }
    } else if (MODE == 0) {
      for (int mt = 0; mt < MT; ++mt) {
        int m = mbase + mt * 16 + quad * 4;
        for (int r = 0; r < 4; ++r)
          ((bf16_t*)C)[(size_t)(m + r) * Ncols + col] = (bf16_t)acc[mt][nt][r];
      }
    } else {  // MODE 2
      const float bv = (float)bias[col];
      const bool obf = (flags[0] != 0);
      for (int mt = 0; mt < MT; ++mt) {
        int m = mbase + mt * 16 + quad * 4;
        for (int r = 0; r < 4; ++r) {
          float v = acc[mt][nt][r] + bv;
          if (obf) ((bf16_t*)C)[(size_t)(m + r) * Ncols + col] = (bf16_t)v;
          else     ((float*)C)[(size_t)(m + r) * Ncols + col] = v;
        }
      }
    }
  }
}

// ---- KV projection (K/V fragment-order epilogues) --------------------------
__launch_bounds__(256, 2)
__global__ void proj_kv(const bf16_t* __restrict__ Yb, const bf16_t* __restrict__ Wkvb,
                        const bf16_t* __restrict__ mmul, bf16_t* __restrict__ Kfr,
                        bf16_t* __restrict__ Vfr) {
  __shared__ __align__(16) char lds[16384];
  gemm_body<768, 1, 128>(lds, Yb, Wkvb, mmul, nullptr, Kfr, Vfr, nullptr, 1024,
                         blockIdx.x, blockIdx.y);
}

// ---- Q projection (MUST run after proj_kv: Qbuf aliases Yb) ----------------
__launch_bounds__(256, 2)
__global__ void proj_q(const bf16_t* __restrict__ Xb, const bf16_t* __restrict__ Wqb,
                       bf16_t* __restrict__ Qbuf) {
  __shared__ __align__(16) char lds[12288];
  gemm_body<512, 0, 64>(lds, Xb, Wqb, nullptr, Qbuf, nullptr, nullptr, nullptr, 512,
                        blockIdx.x, blockIdx.y);
}

// ---- output projection ------------------------------------------------------
__launch_bounds__(256, 2)
__global__ void gemm_out(const bf16_t* __restrict__ Obuf, const bf16_t* __restrict__ Wpb,
                         const bf16_t* __restrict__ bpb, void* __restrict__ out,
                         const int* __restrict__ flags) {
  __shared__ __align__(16) char lds[12288];
  gemm_body<512, 2, 64>(lds, Obuf, Wpb, bpb, out, nullptr, nullptr, flags, 512,
                        blockIdx.x, blockIdx.y);
}

// ---- fused flash attention: barrier-free, 128 q / block, 32 q / wave -------
// K and V read straight from global in MFMA fragment order (L1/L2-hot,
// register double-buffered one tile ahead). No __syncthreads anywhere.
// LDS: only the per-wave 4 KB P round-trip. No online max (scores bounded;
// softmax shift-invariant; exp2 domain via pre-scaled Wq).
__launch_bounds__(256, 2)
__global__ void attn(const bf16_t* __restrict__ Qb, const bf16_t* __restrict__ Kfb,
                     const bf16_t* __restrict__ Vfb, const bf16_t* __restrict__ mmul,
                     bf16_t* __restrict__ Ob) {
  const int t = threadIdx.x, w = t >> 6, lane = t & 63, quad = lane >> 4, l16 = lane & 15;
  const int h = blockIdx.y, b = blockIdx.z;
  const int qw0 = blockIdx.x * 128 + w * 32;  // this wave's 32 q rows

  __shared__ __align__(16) char lds[16384];
  char* Pw = lds + w * 4096;  // 32 rows x 128 B, chunk-swizzled

  // Q B-fragments straight from global (once)
  bf16x8 qf[2][2];
  for (int ng = 0; ng < 2; ++ng)
    for (int kc = 0; kc < 2; ++kc)
      qf[ng][kc] = *(const bf16x8*)(Qb + (size_t)(b * 4096 + qw0 + ng * 16 + l16) * 512
                                    + h * 64 + kc * 32 + quad * 8);

  const char* Kfbase = (const char*)Kfb + (size_t)(b * 8 + h) * 524288;
  const char* Vfbase = (const char*)Vfb + (size_t)(b * 8 + h) * 524288;
  const bf16_t* mbase_p = mmul + b * 4096;

  bf16x8 kf[2][8], vf[2][8], mf[2][2];
  auto load_tile = [&](int p, int kt) {
    const char* Kt = Kfbase + (size_t)kt * 8192;
    const char* Vt = Vfbase + (size_t)kt * 8192;
    for (int i = 0; i < 8; ++i) {
      kf[p][i] = *(const bf16x8*)(Kt + i * 1024 + lane * 16);
      vf[p][i] = *(const bf16x8*)(Vt + i * 1024 + lane * 16);
    }
    mf[p][0] = *(const bf16x8*)(mbase_p + kt * 64 + quad * 8);
    mf[p][1] = *(const bf16x8*)(mbase_p + kt * 64 + 32 + quad * 8);
  };

  load_tile(0, 0);
  f32x4 o[2][4] = {};
  f32x4 lacc[2] = {};

  for (int kt = 0; kt < 64; ++kt) {
    const int p = kt & 1;
    if (kt + 1 < 64) load_tile(p ^ 1, kt + 1);

    // S^T = K·Q^T, P = exp2(S), P -> per-wave LDS (group 0 then group 1;
    // group 1's S work hides group 0's LDS write latency)
    for (int ng = 0; ng < 2; ++ng) {
      const int row = ng * 16 + l16;
      for (int mt = 0; mt < 4; ++mt) {
        f32x4 z = {};
        z = MFMA16(kf[p][mt * 2 + 0], qf[ng][0], z);
        z = MFMA16(kf[p][mt * 2 + 1], qf[ng][1], z);
        bf16x4 pk;
        pk.x = (bf16_t)__builtin_amdgcn_exp2f(z[0]);
        pk.y = (bf16_t)__builtin_amdgcn_exp2f(z[1]);
        pk.z = (bf16_t)__builtin_amdgcn_exp2f(z[2]);
        pk.w = (bf16_t)__builtin_amdgcn_exp2f(z[3]);
        int c2 = (2 * mt + (quad >> 1)) ^ (row & 7);
        *(bf16x4*)(Pw + row * 128 + c2 * 16 + (quad & 1) * 8) = pk;
      }
    }

    // P fragments back (A-operand layout); l via mask MFMA; PV
    bf16x8 pf[2][2];
    for (int ng = 0; ng < 2; ++ng)
      for (int kc = 0; kc < 2; ++kc) {
        int row = ng * 16 + l16;
        int u = (4 * kc + quad) ^ (row & 7);
        pf[ng][kc] = *(const bf16x8*)(Pw + row * 128 + u * 16);
      }
    for (int ng = 0; ng < 2; ++ng) {
      lacc[ng] = MFMA16(pf[ng][0], mf[p][0], lacc[ng]);
      lacc[ng] = MFMA16(pf[ng][1], mf[p][1], lacc[ng]);
    }
    for (int dt = 0; dt < 4; ++dt)
      for (int kc = 0; kc < 2; ++kc) {
        o[0][dt] = MFMA16(pf[0][kc], vf[p][dt * 2 + kc], o[0][dt]);
        o[1][dt] = MFMA16(pf[1][kc], vf[p][dt * 2 + kc], o[1][dt]);
      }
  }

  // epilogue: O / l, store bf16 (C-layout, no shuffles)
  for (int ng = 0; ng < 2; ++ng) {
    float inv[4];
    for (int r = 0; r < 4; ++r) inv[r] = 1.0f / lacc[ng][r];
    for (int dt = 0; dt < 4; ++dt)
      for (int r = 0; r < 4; ++r) {
        int q = qw0 + ng * 16 + quad * 4 + r;
        int col = h * 64 + dt * 16 + l16;
        Ob[(size_t)(b * 4096 + q) * 512 + col] = (bf16_t)(o[ng][dt][r] * inv[r]);
      }
  }
}

// ---- launch ----------------------------------------------------------------
extern "C" void kernel_launch(void* const* d_in, const int* in_sizes, int n_in,
                              void* d_out, int out_size, void* d_ws, size_t ws_size,
                              hipStream_t stream) {
  const void* x   = d_in[0];
  const void* y   = d_in[1];
  const void* msk = d_in[2];
  const void* Wq  = d_in[3];
  const void* Wkv = d_in[4];
  const void* Wp  = d_in[5];
  const void* bp  = d_in[6];

  char* ws = (char*)d_ws;
  bf16_t* Xb   = (bf16_t*)(ws + 0);           //  8 MB  [8192 x 512]
  bf16_t* Yb   = (bf16_t*)(ws + 8388608);     // 12 MB  [8192 x 768]
  bf16_t* Wqb  = (bf16_t*)(ws + 20971520);    // 0.5 MB (pre-scaled by QSCALE)
  bf16_t* Wkvb = (bf16_t*)(ws + 21495808);    // 1.5 MB
  bf16_t* Wpb  = (bf16_t*)(ws + 23068672);    // 0.5 MB
  bf16_t* bpb  = (bf16_t*)(ws + 23592960);    // 1 KB
  bf16_t* mmul = (bf16_t*)(ws + 23593984);    // 16 KB  [2][4096] 0/1
  int*    flags = (int*)(ws + 23610368);      // 64 B
  bf16_t* Kfrag = (bf16_t*)(ws + 25165824);   //  8 MB  A-frag-order K
  bf16_t* Vfrag = (bf16_t*)(ws + 33554432);   //  8 MB  B-frag-order V, mask-zeroed
  bf16_t* Qbuf  = (bf16_t*)(ws + 8388608);    //  8 MB  (aliases Yb -> Q AFTER KV!)
  bf16_t* Obuf  = (bf16_t*)(ws + 0);          //  8 MB  (aliases Xb, dead by then)

  hipLaunchKernelGGL(detect_and_mask, dim3(32), dim3(256), 0, stream,
                     (const uint16_t*)x, (const uint8_t*)msk, flags, mmul);
  hipLaunchKernelGGL(convert_all, dim3(5761), dim3(256), 0, stream,
                     x, y, Wq, Wkv, Wp, bp, (uint16_t*)ws, flags);
  // KV projection (fragment-order K/V epilogues) — must complete before Qbuf write
  hipLaunchKernelGGL(proj_kv, dim3(8, 64), dim3(256), 0, stream,
                     Yb, Wkvb, mmul, Kfrag, Vfrag);
  // Q projection (writes Qbuf, aliasing Yb — Yb dead after proj_kv)
  hipLaunchKernelGGL(proj_q, dim3(8, 64), dim3(256), 0, stream,
                     Xb, Wqb, Qbuf);
  // fused attention: barrier-free, frags from global
  hipLaunchKernelGGL(attn, dim3(32, 8, 2), dim3(256), 0, stream,
                     Qbuf, Kfrag, Vfrag, mmul, Obuf);
  // output projection + bias, dtype per flag
  hipLaunchKernelGGL(gemm_out, dim3(8, 64), dim3(256), 0, stream,
                     Obuf, Wpb, bpb, d_out, flags);
}

// Round 8
// 282.225 us; speedup vs baseline: 4.4181x; 4.4181x over previous
//
#include <hip/hip_runtime.h>
#include <hip/hip_bf16.h>
#include <stdint.h>

// ---- types -----------------------------------------------------------------
typedef __bf16 bf16_t;
typedef __bf16 bf16x8 __attribute__((ext_vector_type(8)));
typedef __bf16 bf16x4 __attribute__((ext_vector_type(4)));
typedef float  f32x4  __attribute__((ext_vector_type(4)));

#define MFMA16(a, b, c) __builtin_amdgcn_mfma_f32_16x16x32_bf16((a), (b), (c), 0, 0, 0)

__device__ __forceinline__ void gload_lds16(const void* g, void* l) {
  __builtin_amdgcn_global_load_lds((const __attribute__((address_space(1))) void*)g,
                                   (__attribute__((address_space(3))) void*)l, 16, 0, 0);
}

// ---- problem constants -----------------------------------------------------
// B=2, N=4096, NY=4096, ENC=768, DEC=512, H=8, D=64, SCALE=0.125
// Wq pre-scaled by SCALE*log2(e): scores live in exp2 domain.
#define QSCALE 0.18033688011112042f
#define NE_X   4194304UL
#define NE_Y   6291456UL
#define NE_WQ  262144UL
#define NE_WKV 786432UL
#define NE_WP  262144UL
#define NE_BP  512UL

// ---- detect dtype + decode mask to multiplicative bf16 (1=keep, 0=masked) --
__global__ void detect_and_mask(const uint16_t* __restrict__ xu,
                                const uint8_t* __restrict__ mk,
                                int* __restrict__ flags, bf16_t* __restrict__ mmul) {
  __shared__ int cbf, c3f1, c3f3, cnz;
  const int t = threadIdx.x;
  if (t == 0) { cbf = 0; c3f1 = 0; c3f3 = 0; cnz = 0; }
  __syncthreads();
  if (blockIdx.x == 0) {
    int local = 0;
    for (int i = t; i < 2048; i += 256) {
      uint16_t u = xu[2 * i];
      int e = (u >> 7) & 0xFF;
      if (u == 0 || (e >= 0x66 && e <= 0x88)) local++;
    }
    atomicAdd(&cbf, local);
  }
  int l1 = 0, l3 = 0, lnz = 0;
  for (int i = t; i < 4096; i += 256) {
    uint8_t b = mk[i];
    int p = i & 3;
    if (p == 1 && b == 0x3F) l1++;
    if (p == 3 && b == 0x3F) l3++;
    if (p != 0 && b != 0) lnz++;
  }
  atomicAdd(&c3f1, l1);
  atomicAdd(&c3f3, l3);
  atomicAdd(&cnz, lnz);
  __syncthreads();
  if (blockIdx.x == 0 && t == 0) flags[0] = (cbf > 1536) ? 1 : 0;
  const int fmt = (c3f1 > 0) ? 2 : (c3f3 > 0) ? 3 : (cnz > 0) ? 0 : 1;  // 0=bool8 1=i32 2=bf16 3=f32
  const int i = blockIdx.x * 256 + t;  // 32 blocks x 256 = 8192
  bool on;
  if (fmt == 0)      on = mk[i] != 0;
  else if (fmt == 1) on = ((const int*)mk)[i] != 0;
  else if (fmt == 2) on = (((const uint16_t*)mk)[i] & 0x7FFF) != 0;
  else               on = ((const float*)mk)[i] != 0.0f;
  mmul[i] = on ? (bf16_t)0.0f : (bf16_t)1.0f;  // mask=true means EXCLUDE
}

// ---- convert all float inputs to packed bf16 workspace (Wq pre-scaled) -----
__global__ void convert_all(const void* __restrict__ x, const void* __restrict__ y,
                            const void* __restrict__ wq, const void* __restrict__ wkv,
                            const void* __restrict__ wp, const void* __restrict__ bp,
                            uint16_t* __restrict__ dst, const int* __restrict__ flags) {
  const size_t E0 = NE_X, E1 = E0 + NE_Y, E2 = E1 + NE_WQ, E3 = E2 + NE_WKV,
               E4 = E3 + NE_WP, E5 = E4 + NE_BP;
  size_t i8 = ((size_t)blockIdx.x * 256 + threadIdx.x) * 8;
  if (i8 >= E5) return;
  const void* src; size_t off;
  if      (i8 < E0) { src = x;   off = i8; }
  else if (i8 < E1) { src = y;   off = i8 - E0; }
  else if (i8 < E2) { src = wq;  off = i8 - E1; }
  else if (i8 < E3) { src = wkv; off = i8 - E2; }
  else if (i8 < E4) { src = wp;  off = i8 - E3; }
  else              { src = bp;  off = i8 - E4; }
  const bool isWq = (i8 >= E1 && i8 < E2);
  if (flags[0] && !isWq) {
    *(uint4*)(dst + i8) = *(const uint4*)((const uint16_t*)src + off);
    return;
  }
  float v[8];
  if (flags[0]) {  // bf16 source (Wq path): unpack
    const uint16_t* u = (const uint16_t*)src + off;
    for (int j = 0; j < 8; ++j) {
      union { uint32_t q; float f; } c; c.q = ((uint32_t)u[j]) << 16; v[j] = c.f;
    }
  } else {
    const float* f = (const float*)src + off;
    float4 a = *(const float4*)f;
    float4 b2 = *(const float4*)(f + 4);
    v[0] = a.x; v[1] = a.y; v[2] = a.z; v[3] = a.w;
    v[4] = b2.x; v[5] = b2.y; v[6] = b2.z; v[7] = b2.w;
  }
  const float sc = isWq ? QSCALE : 1.0f;
  union { bf16_t h[8]; uint4 u; } pk;
  for (int j = 0; j < 8; ++j) pk.h[j] = (bf16_t)(v[j] * sc);
  *(uint4*)(dst + i8) = pk.u;
}

// ---- GEMM body: C[M x Nc] = A[M x K] @ W[Nc x K]^T, 128xBN tile, BK=32 -----
// MODE 0: C = bf16 [M x Ncols].
// MODE 1 (BN=128): cols<512 -> K in MFMA A-frag order:
//           Kf byte = (((b*8+h)*64+kt)*8 + mt*2 + kc)*1024 + lane*16 + j*2
//           with lane=quad*16+l16: key=kt*64+mt*16+l16, d=kc*32+quad*8+j.
//         cols>=512 -> V in MFMA B-frag order, mask-zeroed:
//           Vf byte = (((b*8+h)*64+kt)*8 + dt*2+kc)*1024 + lane*16 + j*2
//           with lane=jq*16+l15: d=dt*16+l15, key=kt*64+kc*32+jq*8+j.
//         `bias` carries mmul (bf16 0/1 per [b*4096+ny]).
// MODE 2: C = output, + bias, fp32 or bf16 per flags[0].
template <int K, int MODE, int BN>
__device__ __forceinline__ void gemm_body(char* lds,
    const bf16_t* __restrict__ A, const bf16_t* __restrict__ W,
    const bf16_t* __restrict__ bias, void* __restrict__ C,
    bf16_t* __restrict__ Kf, bf16_t* __restrict__ Vf,
    const int* __restrict__ flags, int Ncols, int bx, int by) {
  constexpr int MT = (BN == 128) ? 4 : 2;      // m-tiles per wave
  char* ldsA = lds;
  char* ldsW = lds + 8192;
  const int t = threadIdx.x;
  const int w = t >> 6, lane = t & 63, quad = lane >> 4, l16 = lane & 15;
  const int wr = (BN == 128) ? (w >> 1) : w;
  const int wc = (BN == 128) ? (w & 1) : 0;
  const int m0 = by * 128, n0 = bx * BN;

  f32x4 acc[MT][4] = {};
  const int rowS = t >> 2, uS = t & 3;

  for (int k0 = 0; k0 < K; k0 += 32) {
    __syncthreads();
    for (int i = 0; i < 2; ++i) {
      int row = i * 64 + rowS;
      int c = uS ^ ((row >> 1) & 3);
      gload_lds16(A + (size_t)(m0 + row) * K + k0 + c * 8, ldsA + i * 4096 + w * 1024);
    }
    for (int i = 0; i < BN / 64; ++i) {
      int row = i * 64 + rowS;
      int c = uS ^ ((row >> 1) & 3);
      gload_lds16(W + (size_t)(n0 + row) * K + k0 + c * 8, ldsW + i * 4096 + w * 1024);
    }
    __syncthreads();
    bf16x8 af[MT], bfr[4];
    for (int mt = 0; mt < MT; ++mt) {
      int row = wr * (MT * 16) + mt * 16 + l16;
      int us = quad ^ ((row >> 1) & 3);
      af[mt] = *(const bf16x8*)(ldsA + row * 64 + us * 16);
    }
    for (int nt = 0; nt < 4; ++nt) {
      int row = wc * 64 + nt * 16 + l16;
      int us = quad ^ ((row >> 1) & 3);
      bfr[nt] = *(const bf16x8*)(ldsW + row * 64 + us * 16);
    }
    for (int mt = 0; mt < MT; ++mt)
      for (int nt = 0; nt < 4; ++nt)
        acc[mt][nt] = MFMA16(af[mt], bfr[nt], acc[mt][nt]);
  }

  const int mbase = m0 + wr * (MT * 16);
  for (int nt = 0; nt < 4; ++nt) {
    const int col = n0 + wc * 64 + nt * 16 + l16;
    if (MODE == 1 && col >= 512) {
      const int hd = col - 512;                  // h*64 + d
      const int hh = hd >> 6, d = hd & 63;
      const int dt = d >> 4, l15 = d & 15;
      for (int mt = 0; mt < MT; ++mt) {
        int m = mbase + mt * 16 + quad * 4;      // +r over r
        int bb = m >> 12, keyg = m & 4095;
        int kt = keyg >> 6, keyin = keyg & 63;
        int kc = (keyin >> 5) & 1, jq = (keyin >> 3) & 3, j0 = keyin & 7;  // j0 in {0,4}
        const bf16_t* mmp = bias + bb * 4096 + keyg;
        union { bf16_t h4[4]; uint2 u; } pk;
        for (int r = 0; r < 4; ++r) pk.h4[r] = (bf16_t)(acc[mt][nt][r] * (float)mmp[r]);
        size_t base = (((size_t)(bb * 8 + hh) * 64 + kt) * 8 + dt * 2 + kc) * 1024
                      + (jq * 16 + l15) * 16 + j0 * 2;
        *(uint2*)((char*)Vf + base) = pk.u;
      }
    } else if (MODE == 1) {
      // K half -> A-fragment-order scatter (4 x 2B stores per (mt,nt))
      const int hh = col >> 6, d = col & 63;
      const int kc = d >> 5, qd = (d >> 3) & 3, j = d & 7;
      for (int mt = 0; mt < MT; ++mt) {
        int m = mbase + mt * 16 + quad * 4;
        int bb = m >> 12, keyg = m & 4095;
        int kt = keyg >> 6, mtk = (keyg >> 4) & 3, l16k = keyg & 15;  // l16k = quad*4
        char* base = (char*)Kf + (((size_t)(bb * 8 + hh) * 64 + kt) * 8 + mtk * 2 + kc) * 1024
                     + (qd * 16 + l16k) * 16 + j * 2;
        for (int r = 0; r < 4; ++r)
          *(bf16_t*)(base + r * 16) = (bf16_t)acc[mt][nt][r];
      }
    } else if (MODE == 0) {
      for (int mt = 0; mt < MT; ++mt) {
        int m = mbase + mt * 16 + quad * 4;
        for (int r = 0; r < 4; ++r)
          ((bf16_t*)C)[(size_t)(m + r) * Ncols + col] = (bf16_t)acc[mt][nt][r];
      }
    } else {  // MODE 2
      const float bv = (float)bias[col];
      const bool obf = (flags[0] != 0);
      for (int mt = 0; mt < MT; ++mt) {
        int m = mbase + mt * 16 + quad * 4;
        for (int r = 0; r < 4; ++r) {
          float v = acc[mt][nt][r] + bv;
          if (obf) ((bf16_t*)C)[(size_t)(m + r) * Ncols + col] = (bf16_t)v;
          else     ((float*)C)[(size_t)(m + r) * Ncols + col] = v;
        }
      }
    }
  }
}

// ---- KV projection (K/V fragment-order epilogues) --------------------------
__launch_bounds__(256, 2)
__global__ void proj_kv(const bf16_t* __restrict__ Yb, const bf16_t* __restrict__ Wkvb,
                        const bf16_t* __restrict__ mmul, bf16_t* __restrict__ Kfr,
                        bf16_t* __restrict__ Vfr) {
  __shared__ __align__(16) char lds[16384];
  gemm_body<768, 1, 128>(lds, Yb, Wkvb, mmul, nullptr, Kfr, Vfr, nullptr, 1024,
                         blockIdx.x, blockIdx.y);
}

// ---- Q projection (MUST run after proj_kv: Qbuf aliases Yb) ----------------
__launch_bounds__(256, 2)
__global__ void proj_q(const bf16_t* __restrict__ Xb, const bf16_t* __restrict__ Wqb,
                       bf16_t* __restrict__ Qbuf) {
  __shared__ __align__(16) char lds[12288];
  gemm_body<512, 0, 64>(lds, Xb, Wqb, nullptr, Qbuf, nullptr, nullptr, nullptr, 512,
                        blockIdx.x, blockIdx.y);
}

// ---- output projection ------------------------------------------------------
__launch_bounds__(256, 2)
__global__ void gemm_out(const bf16_t* __restrict__ Obuf, const bf16_t* __restrict__ Wpb,
                         const bf16_t* __restrict__ bpb, void* __restrict__ out,
                         const int* __restrict__ flags) {
  __shared__ __align__(16) char lds[12288];
  gemm_body<512, 2, 64>(lds, Obuf, Wpb, bpb, out, nullptr, nullptr, flags, 512,
                        blockIdx.x, blockIdx.y);
}

// ---- fused flash attention: barrier-free, 128 q / block, 32 q / wave -------
// K and V straight from global in MFMA fragment order (L1/L2-hot). K is
// register double-buffered with COMPILE-TIME buffer selection (two named
// buffers + 2x-unrolled loop) — runtime-indexed register arrays spill to
// scratch (R7: 2.1 GB scratch writes). V/mask single-buffered per phase;
// their load latency hides behind S-MFMA+exp+P-roundtrip. No __syncthreads.
__launch_bounds__(256, 2)
__global__ void attn(const bf16_t* __restrict__ Qb, const bf16_t* __restrict__ Kfb,
                     const bf16_t* __restrict__ Vfb, const bf16_t* __restrict__ mmul,
                     bf16_t* __restrict__ Ob) {
  const int t = threadIdx.x, w = t >> 6, lane = t & 63, quad = lane >> 4, l16 = lane & 15;
  const int h = blockIdx.y, b = blockIdx.z;
  const int qw0 = blockIdx.x * 128 + w * 32;  // this wave's 32 q rows

  __shared__ __align__(16) char lds[16384];
  char* Pw = lds + w * 4096;  // 32 rows x 128 B, chunk-swizzled

  // Q B-fragments straight from global (once)
  bf16x8 qf[2][2];
  for (int ng = 0; ng < 2; ++ng)
    for (int kc = 0; kc < 2; ++kc)
      qf[ng][kc] = *(const bf16x8*)(Qb + (size_t)(b * 4096 + qw0 + ng * 16 + l16) * 512
                                    + h * 64 + kc * 32 + quad * 8);

  const char* Kfbase = (const char*)Kfb + (size_t)(b * 8 + h) * 524288;
  const char* Vfbase = (const char*)Vfb + (size_t)(b * 8 + h) * 524288;
  const bf16_t* mbase_p = mmul + b * 4096;

  f32x4 o[2][4] = {};
  f32x4 lacc[2] = {};
  bf16x8 kf0[8], kf1[8];  // named buffers: all indexing compile-time

  {
    const char* Kt = Kfbase;
    for (int i = 0; i < 8; ++i) kf0[i] = *(const bf16x8*)(Kt + i * 1024 + lane * 16);
  }

  // one tile phase: kfb = current K frags (resident), kfn = prefetch target
  auto do_tile = [&](const bf16x8 (&kfb)[8], bf16x8 (&kfn)[8], int kt, bool pref) {
    // V + mask fragments for THIS tile (latency hidden by S/exp below)
    const char* Vt = Vfbase + (size_t)kt * 8192;
    bf16x8 vf[8];
    for (int i = 0; i < 8; ++i) vf[i] = *(const bf16x8*)(Vt + i * 1024 + lane * 16);
    bf16x8 mfa = *(const bf16x8*)(mbase_p + kt * 64 + quad * 8);
    bf16x8 mfb = *(const bf16x8*)(mbase_p + kt * 64 + 32 + quad * 8);
    // prefetch next tile's K frags
    if (pref) {
      const char* Kn = Kfbase + (size_t)(kt + 1) * 8192;
      for (int i = 0; i < 8; ++i) kfn[i] = *(const bf16x8*)(Kn + i * 1024 + lane * 16);
    }
    // S^T = K·Q^T, P = exp2(S), P -> per-wave LDS
    for (int ng = 0; ng < 2; ++ng) {
      const int row = ng * 16 + l16;
      for (int mt = 0; mt < 4; ++mt) {
        f32x4 z = {};
        z = MFMA16(kfb[mt * 2 + 0], qf[ng][0], z);
        z = MFMA16(kfb[mt * 2 + 1], qf[ng][1], z);
        bf16x4 pk;
        pk.x = (bf16_t)__builtin_amdgcn_exp2f(z[0]);
        pk.y = (bf16_t)__builtin_amdgcn_exp2f(z[1]);
        pk.z = (bf16_t)__builtin_amdgcn_exp2f(z[2]);
        pk.w = (bf16_t)__builtin_amdgcn_exp2f(z[3]);
        int c2 = (2 * mt + (quad >> 1)) ^ (row & 7);
        *(bf16x4*)(Pw + row * 128 + c2 * 16 + (quad & 1) * 8) = pk;
      }
    }
    // P fragments back (A-operand layout); l via mask MFMA; PV
    bf16x8 pf[2][2];
    for (int ng = 0; ng < 2; ++ng)
      for (int kc = 0; kc < 2; ++kc) {
        int row = ng * 16 + l16;
        int u = (4 * kc + quad) ^ (row & 7);
        pf[ng][kc] = *(const bf16x8*)(Pw + row * 128 + u * 16);
      }
    lacc[0] = MFMA16(pf[0][0], mfa, lacc[0]);
    lacc[0] = MFMA16(pf[0][1], mfb, lacc[0]);
    lacc[1] = MFMA16(pf[1][0], mfa, lacc[1]);
    lacc[1] = MFMA16(pf[1][1], mfb, lacc[1]);
    for (int dt = 0; dt < 4; ++dt)
      for (int kc = 0; kc < 2; ++kc) {
        o[0][dt] = MFMA16(pf[0][kc], vf[dt * 2 + kc], o[0][dt]);
        o[1][dt] = MFMA16(pf[1][kc], vf[dt * 2 + kc], o[1][dt]);
      }
  };

  for (int kt = 0; kt < 64; kt += 2) {
    do_tile(kf0, kf1, kt, true);
    do_tile(kf1, kf0, kt + 1, kt + 2 < 64);
  }

  // epilogue: O / l, store bf16 (C-layout, no shuffles)
  for (int ng = 0; ng < 2; ++ng) {
    float inv[4];
    for (int r = 0; r < 4; ++r) inv[r] = 1.0f / lacc[ng][r];
    for (int dt = 0; dt < 4; ++dt)
      for (int r = 0; r < 4; ++r) {
        int q = qw0 + ng * 16 + quad * 4 + r;
        int col = h * 64 + dt * 16 + l16;
        Ob[(size_t)(b * 4096 + q) * 512 + col] = (bf16_t)(o[ng][dt][r] * inv[r]);
      }
  }
}

// ---- launch ----------------------------------------------------------------
extern "C" void kernel_launch(void* const* d_in, const int* in_sizes, int n_in,
                              void* d_out, int out_size, void* d_ws, size_t ws_size,
                              hipStream_t stream) {
  const void* x   = d_in[0];
  const void* y   = d_in[1];
  const void* msk = d_in[2];
  const void* Wq  = d_in[3];
  const void* Wkv = d_in[4];
  const void* Wp  = d_in[5];
  const void* bp  = d_in[6];

  char* ws = (char*)d_ws;
  bf16_t* Xb   = (bf16_t*)(ws + 0);           //  8 MB  [8192 x 512]
  bf16_t* Yb   = (bf16_t*)(ws + 8388608);     // 12 MB  [8192 x 768]
  bf16_t* Wqb  = (bf16_t*)(ws + 20971520);    // 0.5 MB (pre-scaled by QSCALE)
  bf16_t* Wkvb = (bf16_t*)(ws + 21495808);    // 1.5 MB
  bf16_t* Wpb  = (bf16_t*)(ws + 23068672);    // 0.5 MB
  bf16_t* bpb  = (bf16_t*)(ws + 23592960);    // 1 KB
  bf16_t* mmul = (bf16_t*)(ws + 23593984);    // 16 KB  [2][4096] 0/1
  int*    flags = (int*)(ws + 23610368);      // 64 B
  bf16_t* Kfrag = (bf16_t*)(ws + 25165824);   //  8 MB  A-frag-order K
  bf16_t* Vfrag = (bf16_t*)(ws + 33554432);   //  8 MB  B-frag-order V, mask-zeroed
  bf16_t* Qbuf  = (bf16_t*)(ws + 8388608);    //  8 MB  (aliases Yb -> Q AFTER KV!)
  bf16_t* Obuf  = (bf16_t*)(ws + 0);          //  8 MB  (aliases Xb, dead by then)

  hipLaunchKernelGGL(detect_and_mask, dim3(32), dim3(256), 0, stream,
                     (const uint16_t*)x, (const uint8_t*)msk, flags, mmul);
  hipLaunchKernelGGL(convert_all, dim3(5761), dim3(256), 0, stream,
                     x, y, Wq, Wkv, Wp, bp, (uint16_t*)ws, flags);
  // KV projection (fragment-order K/V epilogues) — must complete before Qbuf write
  hipLaunchKernelGGL(proj_kv, dim3(8, 64), dim3(256), 0, stream,
                     Yb, Wkvb, mmul, Kfrag, Vfrag);
  // Q projection (writes Qbuf, aliasing Yb — Yb dead after proj_kv)
  hipLaunchKernelGGL(proj_q, dim3(8, 64), dim3(256), 0, stream,
                     Xb, Wqb, Qbuf);
  // fused attention: barrier-free, frags from global
  hipLaunchKernelGGL(attn, dim3(32, 8, 2), dim3(256), 0, stream,
                     Qbuf, Kfrag, Vfrag, mmul, Obuf);
  // output projection + bias, dtype per flag
  hipLaunchKernelGGL(gemm_out, dim3(8, 64), dim3(256), 0, stream,
                     Obuf, Wpb, bpb, d_out, flags);
}